// Round 11
// baseline (160.500 us; speedup 1.0000x reference)
//
#include <hip/hip_runtime.h>
#include <cstdint>

// MultiheadRCDA: N=8, L=300, HH=WW=96, E=256, NH=8, HD=32
// Round 11: vproj v9 — B pinned in AGPRs ("+a"; MFMA reads B from AGPR on
// gfx950), 4-tile store grouping (128B contiguous per channel -> no RFO /
// partial-line evictions; r10 FETCH≈vvT size proved RFO), grid 256 (1/CU,
// uniform), 18 tiles/block, depth-2 GLL pipeline with exact counted vmcnt.

typedef __attribute__((ext_vector_type(8))) short short8v;  // bf16x8 MFMA frag
typedef __attribute__((ext_vector_type(4))) short short4v;  // 8B packed bf16
typedef __attribute__((ext_vector_type(4))) float f32x4;

#define SCALE_Q 0.17677669529663687f  // 32^-0.5

#define GLL16(gp, lp)                                                   \
  __builtin_amdgcn_global_load_lds(                                     \
      (const __attribute__((address_space(1))) void*)(gp),              \
      (__attribute__((address_space(3))) void*)(lp), 16, 0, 0)

__device__ __forceinline__ unsigned short f2bf(float x) {
  unsigned int u = __builtin_bit_cast(unsigned int, x);
  u += 0x7FFFu + ((u >> 16) & 1u);
  return (unsigned short)(u >> 16);
}

__device__ __forceinline__ unsigned int cvtpk(float a, float b) {
  unsigned int r;
  asm("v_cvt_pk_bf16_f32 %0, %1, %2" : "=v"(r) : "v"(a), "v"(b));
  return r;
}

__device__ __forceinline__ short8v pack8cvt(const f32x4& lo, const f32x4& hi) {
  union { short8v s; unsigned int u[4]; } z;
  z.u[0] = cvtpk(lo[0], lo[1]);
  z.u[1] = cvtpk(lo[2], lo[3]);
  z.u[2] = cvtpk(hi[0], hi[1]);
  z.u[3] = cvtpk(hi[2], hi[3]);
  return z.s;
}

__device__ __forceinline__ short4v pack4cvt(float a, float b, float c, float d) {
  union { short4v s; unsigned int u[2]; } z;
  z.u[0] = cvtpk(a, b);
  z.u[1] = cvtpk(c, d);
  return z.s;
}

__device__ __forceinline__ short8v pack8(const float4& fa, const float4& fb) {
  short8v v;
  v[0] = (short)f2bf(fa.x); v[1] = (short)f2bf(fa.y);
  v[2] = (short)f2bf(fa.z); v[3] = (short)f2bf(fa.w);
  v[4] = (short)f2bf(fb.x); v[5] = (short)f2bf(fb.y);
  v[6] = (short)f2bf(fb.z); v[7] = (short)f2bf(fb.w);
  return v;
}

// ---------------- weight fp32->bf16 ----------------
__global__ __launch_bounds__(256) void cvt_w_kernel(const float* __restrict__ w_in,
                                                    const float* __restrict__ w_out,
                                                    short* __restrict__ Wb) {
  int idx = blockIdx.x * 256 + threadIdx.x;  // 393216 total
  float v = (idx < 327680) ? w_in[idx] : w_out[idx - 327680];
  Wb[idx] = (short)f2bf(v);
}

// ---------------- mean kernels v3 ----------------
__global__ __launch_bounds__(256) void mean_over_h_v3(const float* __restrict__ in,
                                                      float* __restrict__ out) {
  __shared__ float4 part[256];
  int bw = blockIdx.x;  // b*96 + w
  int b = bw / 96, w = bw - b * 96;
  int t = threadIdx.x, e4 = t & 63, hq = t >> 6;
  const float4* p = (const float4*)(in + ((size_t)b * 9216 + w) * 256) + e4 +
                    (size_t)hq * 24 * 6144;
  float4 s = {0.f, 0.f, 0.f, 0.f};
#pragma unroll
  for (int i = 0; i < 24; ++i) {
    float4 v = p[(size_t)i * 6144];
    s.x += v.x; s.y += v.y; s.z += v.z; s.w += v.w;
  }
  part[t] = s;
  __syncthreads();
  if (t < 64) {
    float4 a = part[t], c = part[t + 64], d = part[t + 128], e = part[t + 192];
    float4 o;
    o.x = (a.x + c.x + d.x + e.x) * (1.f / 96.f);
    o.y = (a.y + c.y + d.y + e.y) * (1.f / 96.f);
    o.z = (a.z + c.z + d.z + e.z) * (1.f / 96.f);
    o.w = (a.w + c.w + d.w + e.w) * (1.f / 96.f);
    ((float4*)out)[(size_t)bw * 64 + t] = o;
  }
}

__global__ __launch_bounds__(256) void mean_over_w_v3(const float* __restrict__ in,
                                                      float* __restrict__ out) {
  __shared__ float4 part[256];
  int bh = blockIdx.x;  // b*96 + h
  int t = threadIdx.x, e4 = t & 63, wq = t >> 6;
  const float4* p = (const float4*)(in + (size_t)bh * 24576) + e4 + (size_t)wq * 24 * 64;
  float4 s = {0.f, 0.f, 0.f, 0.f};
#pragma unroll
  for (int i = 0; i < 24; ++i) {
    float4 v = p[(size_t)i * 64];
    s.x += v.x; s.y += v.y; s.z += v.z; s.w += v.w;
  }
  part[t] = s;
  __syncthreads();
  if (t < 64) {
    float4 a = part[t], c = part[t + 64], d = part[t + 128], e = part[t + 192];
    float4 o;
    o.x = (a.x + c.x + d.x + e.x) * (1.f / 96.f);
    o.y = (a.y + c.y + d.y + e.y) * (1.f / 96.f);
    o.z = (a.z + c.z + d.z + e.z) * (1.f / 96.f);
    o.w = (a.w + c.w + d.w + e.w) * (1.f / 96.f);
    ((float4*)out)[(size_t)bh * 64 + t] = o;
  }
}

// ---------------- bf16 MFMA projection GEMM (q/k/out), BM=32 ----------------
__global__ __launch_bounds__(256) void gemm_proj(
    const float* __restrict__ A0, const float* __restrict__ A1,
    const short* __restrict__ Wb, const float* __restrict__ bias,
    float* __restrict__ Cf, short* __restrict__ Cb0, short* __restrict__ Cb1,
    float scale, int mode) {
  __shared__ short As[32 * 264];
  int y = blockIdx.y;
  const float* A = y ? A1 : A0;
  short* Cb = y ? Cb1 : Cb0;
  const short* Wp = Wb + y * 65536;
  const float* bp = bias + y * 256;
  int t = threadIdx.x;
  int m0 = blockIdx.x * 32;
  int wave = t >> 6, lane = t & 63, r = lane & 15, g = lane >> 4;

  {
    int row = t >> 3, c0 = (t & 7) * 32;
    const float* ap = A + ((size_t)m0 + row) * 256 + c0;
    float4 ld[8];
#pragma unroll
    for (int j = 0; j < 8; ++j) ld[j] = *(const float4*)(ap + j * 4);
    short* dst = &As[row * 264 + c0];
#pragma unroll
    for (int j = 0; j < 4; ++j)
      *(short8v*)(dst + j * 8) = pack8(ld[2 * j], ld[2 * j + 1]);
  }
  __syncthreads();

  f32x4 acc[2][4] = {};
  const short* wbase = Wp + (size_t)(wave * 64 + r) * 256;
#pragma unroll
  for (int ks = 0; ks < 8; ++ks) {
    short8v af0 = *(const short8v*)&As[r * 264 + ks * 32 + g * 8];
    short8v af1 = *(const short8v*)&As[(16 + r) * 264 + ks * 32 + g * 8];
    short8v bf[4];
#pragma unroll
    for (int nf = 0; nf < 4; ++nf)
      bf[nf] = *(const short8v*)(wbase + nf * 16 * 256 + ks * 32 + g * 8);
#pragma unroll
    for (int nf = 0; nf < 4; ++nf) {
      acc[0][nf] = __builtin_amdgcn_mfma_f32_16x16x32_bf16(af0, bf[nf], acc[0][nf], 0, 0, 0);
      acc[1][nf] = __builtin_amdgcn_mfma_f32_16x16x32_bf16(af1, bf[nf], acc[1][nf], 0, 0, 0);
    }
  }

#pragma unroll
  for (int mf = 0; mf < 2; ++mf)
#pragma unroll
    for (int nf = 0; nf < 4; ++nf) {
      int nn = wave * 64 + nf * 16 + r;
      float bval = bp[nn];
#pragma unroll
      for (int i = 0; i < 4; ++i) {
        int m = m0 + mf * 16 + g * 4 + i;
        float val = (acc[mf][nf][i] + bval) * scale;
        if (mode == 1) {
          int bb = m / 300, ll = m - bb * 300;
          Cf[((size_t)ll * 8 + bb) * 256 + nn] = val;
        } else {  // mode 3
          Cb[(size_t)m * 256 + nn] = (short)f2bf(val);
        }
      }
    }
}

// ---------------- value projection v9 ----------------
// vvT[bn][d(32)][hw(9216)] bf16. grid 256 (1 block/CU), 288 rows/block
// (18 tiles of 16). B in AGPRs; depth-2 GLL pipeline; 4-tile store groups
// (128B contiguous per channel -> full-line writes, no RFO).
__global__ __launch_bounds__(256, 2) void vproj_kernel(
    const float* __restrict__ A, const short* __restrict__ Wb,
    const float* __restrict__ bias, short* __restrict__ vvT) {
  __shared__ float buf[2][16 * 260];   // 33.3 KB, row stride 260 floats
  __shared__ short Ts[4][64 * 68];     // per-wave 64ch x (64hw pad68) = 34.8 KB
  int t = threadIdx.x;
  int wave = t >> 6, lane = t & 63, r = lane & 15, g = lane >> 4;
  int m0g = blockIdx.x * 288;          // global row base (= b*9216 + hw00)
  int b_ = blockIdx.x >> 5;            // 32 blocks per batch (9216/288)
  int hw00 = (blockIdx.x & 31) * 288;

  // hoist B (wave's 64 output channels, full K) and pin in AGPRs:
  // gfx950 MFMA reads B from AGPR natively; AGPR home can't be rematerialized
  // or spilled to scratch (r9/r10: "+v" pin failed, VGPR_Count 84/92 < 128).
  short8v bf[8][4];
  {
    const short* wbase = Wb + (size_t)(wave * 64 + r) * 256;
#pragma unroll
    for (int ks = 0; ks < 8; ++ks)
#pragma unroll
      for (int nf = 0; nf < 4; ++nf)
        bf[ks][nf] = *(const short8v*)(wbase + nf * 16 * 256 + ks * 32 + g * 8);
  }
#pragma unroll
  for (int ks = 0; ks < 8; ++ks)
#pragma unroll
    for (int nf = 0; nf < 4; ++nf)
      asm volatile("" : "+a"(bf[ks][nf]));
  float bias_v[4];
#pragma unroll
  for (int nf = 0; nf < 4; ++nf) bias_v[nf] = bias[wave * 64 + nf * 16 + r];

  // prologue: stage tiles 0,1 (wave w stages rows 4w..4w+3 of each tile)
#pragma unroll
  for (int q = 0; q < 2; ++q) {
#pragma unroll
    for (int i = 0; i < 4; ++i) {
      int row = wave * 4 + i;
      const float* gp = A + ((size_t)m0g + q * 16 + row) * 256 + lane * 4;
      GLL16(gp, &buf[q][row * 260]);
    }
  }

  int chg = wave * 64 + lane;  // lane's output channel
  short* vbase = vvT + (size_t)(b_ * 8 + (chg >> 5)) * 294912 +
                 (size_t)(chg & 31) * 9216 + hw00;
  const short* tsr = &Ts[wave][lane * 68];

#pragma unroll
  for (int tt = 0; tt < 18; ++tt) {
    // counted wait for tile tt's 4 GLLs (in-order vmcnt retirement):
    // after-issued ops = next refill GLLs (4) normally; +8 stores right after
    // a store-iter; final tile drains.
    if (tt == 17)                    asm volatile("s_waitcnt vmcnt(0)" ::: "memory");
    else if ((tt & 3) == 0 && tt)    asm volatile("s_waitcnt vmcnt(12)" ::: "memory");
    else                             asm volatile("s_waitcnt vmcnt(4)" ::: "memory");
    __builtin_amdgcn_s_barrier();  // all waves' rows of tile tt present

    // compute tile tt from buf[tt&1]
    f32x4 acc[4] = {};
    const float* bp_ = &buf[tt & 1][0];
#pragma unroll
    for (int ks = 0; ks < 8; ++ks) {
      const float* p = bp_ + r * 260 + ks * 32 + g * 8;
      f32x4 lo = *(const f32x4*)p;
      f32x4 hi = *(const f32x4*)(p + 4);
      short8v af = pack8cvt(lo, hi);
#pragma unroll
      for (int nf = 0; nf < 4; ++nf)
        acc[nf] = __builtin_amdgcn_mfma_f32_16x16x32_bf16(af, bf[ks][nf], acc[nf], 0, 0, 0);
    }

    // accumulate into per-wave Ts at hw slot (tt&3)*16 (DS in-order per wave)
#pragma unroll
    for (int nf = 0; nf < 4; ++nf) {
      float bv = bias_v[nf];
      *(short4v*)&Ts[wave][(nf * 16 + r) * 68 + (tt & 3) * 16 + g * 4] =
          pack4cvt(acc[nf][0] + bv, acc[nf][1] + bv, acc[nf][2] + bv, acc[nf][3] + bv);
    }
    asm volatile("" ::: "memory");

    // store phase every 4 tiles: 128B contiguous per channel (2 full lines)
    if ((tt & 3) == 3) {
      short* gdst = vbase + (tt >> 2) * 64;
#pragma unroll
      for (int j = 0; j < 8; ++j)
        *(short8v*)(gdst + j * 8) = *(const short8v*)(tsr + j * 8);
      asm volatile("" ::: "memory");
    } else if (tt == 17) {  // final partial group: tiles 16,17 = 32 hw
      short* gdst = vbase + 256;
#pragma unroll
      for (int j = 0; j < 4; ++j)
        *(short8v*)(gdst + j * 8) = *(const short8v*)(tsr + j * 8);
      asm volatile("" ::: "memory");
    }

    __builtin_amdgcn_s_barrier();  // all waves done reading buf[tt&1]
    if (tt + 2 < 18) {             // refill with tile tt+2
#pragma unroll
      for (int i = 0; i < 4; ++i) {
        int row = wave * 4 + i;
        const float* gp = A + ((size_t)m0g + (tt + 2) * 16 + row) * 256 + lane * 4;
        GLL16(gp, &buf[tt & 1][row * 260]);
      }
    }
  }
}

// ---------------- scores + softmax: MFMA + in-register softmax ----------------
__global__ __launch_bounds__(64) void scores_softmax_v2(
    const short* __restrict__ qrb, const short* __restrict__ qcb,
    const short* __restrict__ krb, const short* __restrict__ kcb,
    short* __restrict__ wrowB, float* __restrict__ wcolT) {
  int lchunk = blockIdx.x, bn = blockIdx.y, kind = blockIdx.z;
  int b = bn >> 3, n = bn & 7;
  int lane = threadIdx.x;
  int r = lane & 15, g = lane >> 4;
  const short* qb = kind ? qcb : qrb;
  const short* kb = kind ? kcb : krb;
  int l0 = lchunk * 80;

  short8v a[5], bfr[6];
#pragma unroll
  for (int lf = 0; lf < 5; ++lf) {
    int l = l0 + lf * 16 + r;
    if (l > 299) l = 299;
    a[lf] = *(const short8v*)(qb + ((size_t)b * 300 + l) * 256 + n * 32 + g * 8);
  }
#pragma unroll
  for (int f = 0; f < 6; ++f)
    bfr[f] = *(const short8v*)(kb + ((size_t)b * 96 + f * 16 + r) * 256 + n * 32 + g * 8);

  f32x4 c[5][6];
#pragma unroll
  for (int lf = 0; lf < 5; ++lf)
#pragma unroll
    for (int f = 0; f < 6; ++f) {
      f32x4 z = {};
      c[lf][f] = __builtin_amdgcn_mfma_f32_16x16x32_bf16(a[lf], bfr[f], z, 0, 0, 0);
    }

#pragma unroll
  for (int lf = 0; lf < 5; ++lf)
#pragma unroll
    for (int i = 0; i < 4; ++i) {
      float m = c[lf][0][i];
#pragma unroll
      for (int f = 1; f < 6; ++f) m = fmaxf(m, c[lf][f][i]);
#pragma unroll
      for (int mask = 1; mask <= 8; mask <<= 1) m = fmaxf(m, __shfl_xor(m, mask, 64));
      float e[6], s = 0.f;
#pragma unroll
      for (int f = 0; f < 6; ++f) { e[f] = __expf(c[lf][f][i] - m); s += e[f]; }
#pragma unroll
      for (int mask = 1; mask <= 8; mask <<= 1) s += __shfl_xor(s, mask, 64);
      float inv = 1.f / s;
#pragma unroll
      for (int f = 0; f < 6; ++f) c[lf][f][i] = e[f] * inv;
    }

  if (kind == 0) {
#pragma unroll
    for (int lf = 0; lf < 5; ++lf)
#pragma unroll
      for (int i = 0; i < 4; ++i) {
        int l = l0 + lf * 16 + g * 4 + i;
        bool ok = (l < 300);
#pragma unroll
        for (int f = 0; f < 6; ++f) {
          float wv = ok ? c[lf][f][i] : 0.f;
          wrowB[((size_t)bn * 320 + l) * 96 + f * 16 + r] = (short)f2bf(wv);
        }
      }
  } else {
#pragma unroll
    for (int lf = 0; lf < 5; ++lf)
#pragma unroll
      for (int f = 0; f < 6; ++f) {
        int l = l0 + lf * 16 + g * 4;
        f32x4 wv = c[lf][f];
#pragma unroll
        for (int i = 0; i < 4; ++i) if (l + i >= 300) wv[i] = 0.f;
        *(f32x4*)(wcolT + ((size_t)bn * 96 + f * 16 + r) * 320 + l) = wv;
      }
  }
}

// ---------------- fused bilinear attention (MFMA, 8 waves) ----------------
__global__ __launch_bounds__(512) void attn_kernel(
    const short* __restrict__ wrowB, const float* __restrict__ wcolT,
    const short* __restrict__ vvT, float* __restrict__ ao) {
  __shared__ f32x4 cmb[3][2][4][64];
  int lh = blockIdx.x, n = blockIdx.y, b = blockIdx.z;
  int bn = b * 8 + n;
  int t = threadIdx.x, wave = t >> 6, lane = t & 63;
  int df = wave & 1, hh = wave >> 1;
  int lbase = lh * 64;
  int r = lane & 15, g = lane >> 4;

  short8v a[4][3];
  const short* wr = wrowB + (size_t)bn * 320 * 96;
#pragma unroll
  for (int lf = 0; lf < 4; ++lf)
#pragma unroll
    for (int ks = 0; ks < 3; ++ks)
      a[lf][ks] = *(const short8v*)(wr + (lbase + lf * 16 + r) * 96 + ks * 32 + g * 8);

  const short* vb = vvT + (size_t)bn * 294912 + (size_t)(df * 16 + r) * 9216 + hh * 24 * 96;
  const float* wcb = wcolT + ((size_t)bn * 96 + hh * 24) * 320 + lbase + g * 4;

  f32x4 acc[4] = {};
  short8v b0[3], b1[3];
  f32x4 w0[4], w1[4];
#pragma unroll
  for (int ks = 0; ks < 3; ++ks) b0[ks] = *(const short8v*)(vb + ks * 32 + g * 8);
#pragma unroll
  for (int lf = 0; lf < 4; ++lf) w0[lf] = *(const f32x4*)(wcb + lf * 16);

  for (int h2 = 0; h2 < 12; ++h2) {
    int h = h2 * 2;
#pragma unroll
    for (int ks = 0; ks < 3; ++ks) b1[ks] = *(const short8v*)(vb + (h + 1) * 96 + ks * 32 + g * 8);
#pragma unroll
    for (int lf = 0; lf < 4; ++lf) w1[lf] = *(const f32x4*)(wcb + (h + 1) * 320 + lf * 16);
    {
      f32x4 R[4] = {};
#pragma unroll
      for (int ks = 0; ks < 3; ++ks)
#pragma unroll
        for (int lf = 0; lf < 4; ++lf)
          R[lf] = __builtin_amdgcn_mfma_f32_16x16x32_bf16(a[lf][ks], b0[ks], R[lf], 0, 0, 0);
#pragma unroll
      for (int lf = 0; lf < 4; ++lf) acc[lf] += w0[lf] * R[lf];
    }
    if (h2 < 11) {
#pragma unroll
      for (int ks = 0; ks < 3; ++ks) b0[ks] = *(const short8v*)(vb + (h + 2) * 96 + ks * 32 + g * 8);
#pragma unroll
      for (int lf = 0; lf < 4; ++lf) w0[lf] = *(const f32x4*)(wcb + (h + 2) * 320 + lf * 16);
    }
    {
      f32x4 R[4] = {};
#pragma unroll
      for (int ks = 0; ks < 3; ++ks)
#pragma unroll
        for (int lf = 0; lf < 4; ++lf)
          R[lf] = __builtin_amdgcn_mfma_f32_16x16x32_bf16(a[lf][ks], b1[ks], R[lf], 0, 0, 0);
#pragma unroll
      for (int lf = 0; lf < 4; ++lf) acc[lf] += w1[lf] * R[lf];
    }
  }

  if (hh > 0) {
#pragma unroll
    for (int lf = 0; lf < 4; ++lf) cmb[hh - 1][df][lf][lane] = acc[lf];
  }
  __syncthreads();
  if (hh == 0) {
#pragma unroll
    for (int lf = 0; lf < 4; ++lf) {
      f32x4 o = acc[lf];
#pragma unroll
      for (int q = 0; q < 3; ++q) o += cmb[q][df][lf][lane];
#pragma unroll
      for (int i = 0; i < 4; ++i) {
        int l = lbase + lf * 16 + g * 4 + i;
        if (l < 300)
          ao[((size_t)b * 300 + l) * 256 + n * 32 + df * 16 + r] = o[i];
      }
    }
  }
}

// ---------------- launch ----------------
extern "C" void kernel_launch(void* const* d_in, const int* in_sizes, int n_in,
                              void* d_out, int out_size, void* d_ws, size_t ws_size,
                              hipStream_t stream) {
  const float* query_row = (const float*)d_in[0];
  const float* query_col = (const float*)d_in[1];
  const float* key_row   = (const float*)d_in[2];
  const float* key_col   = (const float*)d_in[3];
  const float* value     = (const float*)d_in[4];
  const float* W         = (const float*)d_in[5];  // (1280,256)
  const float* Bv        = (const float*)d_in[6];  // (1280,)
  const float* Wout      = (const float*)d_in[7];  // (256,256)
  const float* Bout      = (const float*)d_in[8];  // (256,)

  float* ws = (float*)d_ws;
  float* krm   = ws;                        // 196608 f
  float* kcm   = krm + 196608;              // 196608 f
  float* ao    = kcm + 196608;              // 614400 f
  float* wcolT = ao + 614400;               // 1966080 f
  short* qrb   = (short*)(wcolT + 1966080); // 614400 s
  short* qcb   = qrb + 614400;              // 614400 s
  short* krb   = qcb + 614400;              // 196608 s
  short* kcb   = krb + 196608;              // 196608 s
  short* wrowB = kcb + 196608;              // 1966080 s
  short* vvT   = wrowB + 1966080;           // 18874368 s
  short* Wb    = vvT + 18874368;            // 393216 s

  cvt_w_kernel<<<1536, 256, 0, stream>>>(W, Wout, Wb);
  mean_over_h_v3<<<768, 256, 0, stream>>>(key_row, krm);
  mean_over_w_v3<<<768, 256, 0, stream>>>(key_col, kcm);
  gemm_proj<<<dim3(75, 2), 256, 0, stream>>>(query_row, query_col, Wb, Bv,
                                             nullptr, qrb, qcb, SCALE_Q, 3);
  gemm_proj<<<dim3(24, 2), 256, 0, stream>>>(krm, kcm, Wb + 131072, Bv + 512,
                                             nullptr, krb, kcb, 1.f, 3);
  vproj_kernel<<<256, 256, 0, stream>>>(value, Wb + 262144, Bv + 1024, vvT);
  scores_softmax_v2<<<dim3(4, 64, 2), 64, 0, stream>>>(qrb, qcb, krb, kcb, wrowB, wcolT);
  attn_kernel<<<dim3(5, 8, 8), 512, 0, stream>>>(wrowB, wcolT, vvT, ao);
  gemm_proj<<<dim3(75, 1), 256, 0, stream>>>(ao, nullptr, Wb + 327680, Bout,
                                             (float*)d_out, nullptr, nullptr, 1.f, 1);
}

// Round 12
// 159.560 us; speedup vs baseline: 1.0059x; 1.0059x over previous
//
#include <hip/hip_runtime.h>
#include <cstdint>

// MultiheadRCDA: N=8, L=300, HH=WW=96, E=256, NH=8, HD=32
// Round 12: attn XCD-bn swizzle (5 lh-blocks sharing a bn -> same XCD L2;
// r11 FETCH=98MB vs 37.7MB vvT proved cross-XCD re-fetch). vproj v10: 8 waves
// x 32 channels (2 waves/SIMD hides LDS latency; B traffic unchanged).

typedef __attribute__((ext_vector_type(8))) short short8v;  // bf16x8 MFMA frag
typedef __attribute__((ext_vector_type(4))) short short4v;  // 8B packed bf16
typedef __attribute__((ext_vector_type(4))) float f32x4;

#define SCALE_Q 0.17677669529663687f  // 32^-0.5

#define GLL16(gp, lp)                                                   \
  __builtin_amdgcn_global_load_lds(                                     \
      (const __attribute__((address_space(1))) void*)(gp),              \
      (__attribute__((address_space(3))) void*)(lp), 16, 0, 0)

__device__ __forceinline__ unsigned short f2bf(float x) {
  unsigned int u = __builtin_bit_cast(unsigned int, x);
  u += 0x7FFFu + ((u >> 16) & 1u);
  return (unsigned short)(u >> 16);
}

__device__ __forceinline__ unsigned int cvtpk(float a, float b) {
  unsigned int r;
  asm("v_cvt_pk_bf16_f32 %0, %1, %2" : "=v"(r) : "v"(a), "v"(b));
  return r;
}

__device__ __forceinline__ short8v pack8cvt(const f32x4& lo, const f32x4& hi) {
  union { short8v s; unsigned int u[4]; } z;
  z.u[0] = cvtpk(lo[0], lo[1]);
  z.u[1] = cvtpk(lo[2], lo[3]);
  z.u[2] = cvtpk(hi[0], hi[1]);
  z.u[3] = cvtpk(hi[2], hi[3]);
  return z.s;
}

__device__ __forceinline__ short4v pack4cvt(float a, float b, float c, float d) {
  union { short4v s; unsigned int u[2]; } z;
  z.u[0] = cvtpk(a, b);
  z.u[1] = cvtpk(c, d);
  return z.s;
}

__device__ __forceinline__ short8v pack8(const float4& fa, const float4& fb) {
  short8v v;
  v[0] = (short)f2bf(fa.x); v[1] = (short)f2bf(fa.y);
  v[2] = (short)f2bf(fa.z); v[3] = (short)f2bf(fa.w);
  v[4] = (short)f2bf(fb.x); v[5] = (short)f2bf(fb.y);
  v[6] = (short)f2bf(fb.z); v[7] = (short)f2bf(fb.w);
  return v;
}

// ---------------- weight fp32->bf16 ----------------
__global__ __launch_bounds__(256) void cvt_w_kernel(const float* __restrict__ w_in,
                                                    const float* __restrict__ w_out,
                                                    short* __restrict__ Wb) {
  int idx = blockIdx.x * 256 + threadIdx.x;  // 393216 total
  float v = (idx < 327680) ? w_in[idx] : w_out[idx - 327680];
  Wb[idx] = (short)f2bf(v);
}

// ---------------- mean kernels v3 ----------------
__global__ __launch_bounds__(256) void mean_over_h_v3(const float* __restrict__ in,
                                                      float* __restrict__ out) {
  __shared__ float4 part[256];
  int bw = blockIdx.x;  // b*96 + w
  int b = bw / 96, w = bw - b * 96;
  int t = threadIdx.x, e4 = t & 63, hq = t >> 6;
  const float4* p = (const float4*)(in + ((size_t)b * 9216 + w) * 256) + e4 +
                    (size_t)hq * 24 * 6144;
  float4 s = {0.f, 0.f, 0.f, 0.f};
#pragma unroll
  for (int i = 0; i < 24; ++i) {
    float4 v = p[(size_t)i * 6144];
    s.x += v.x; s.y += v.y; s.z += v.z; s.w += v.w;
  }
  part[t] = s;
  __syncthreads();
  if (t < 64) {
    float4 a = part[t], c = part[t + 64], d = part[t + 128], e = part[t + 192];
    float4 o;
    o.x = (a.x + c.x + d.x + e.x) * (1.f / 96.f);
    o.y = (a.y + c.y + d.y + e.y) * (1.f / 96.f);
    o.z = (a.z + c.z + d.z + e.z) * (1.f / 96.f);
    o.w = (a.w + c.w + d.w + e.w) * (1.f / 96.f);
    ((float4*)out)[(size_t)bw * 64 + t] = o;
  }
}

__global__ __launch_bounds__(256) void mean_over_w_v3(const float* __restrict__ in,
                                                      float* __restrict__ out) {
  __shared__ float4 part[256];
  int bh = blockIdx.x;  // b*96 + h
  int t = threadIdx.x, e4 = t & 63, wq = t >> 6;
  const float4* p = (const float4*)(in + (size_t)bh * 24576) + e4 + (size_t)wq * 24 * 64;
  float4 s = {0.f, 0.f, 0.f, 0.f};
#pragma unroll
  for (int i = 0; i < 24; ++i) {
    float4 v = p[(size_t)i * 64];
    s.x += v.x; s.y += v.y; s.z += v.z; s.w += v.w;
  }
  part[t] = s;
  __syncthreads();
  if (t < 64) {
    float4 a = part[t], c = part[t + 64], d = part[t + 128], e = part[t + 192];
    float4 o;
    o.x = (a.x + c.x + d.x + e.x) * (1.f / 96.f);
    o.y = (a.y + c.y + d.y + e.y) * (1.f / 96.f);
    o.z = (a.z + c.z + d.z + e.z) * (1.f / 96.f);
    o.w = (a.w + c.w + d.w + e.w) * (1.f / 96.f);
    ((float4*)out)[(size_t)bh * 64 + t] = o;
  }
}

// ---------------- bf16 MFMA projection GEMM (q/k/out), BM=32 ----------------
__global__ __launch_bounds__(256) void gemm_proj(
    const float* __restrict__ A0, const float* __restrict__ A1,
    const short* __restrict__ Wb, const float* __restrict__ bias,
    float* __restrict__ Cf, short* __restrict__ Cb0, short* __restrict__ Cb1,
    float scale, int mode) {
  __shared__ short As[32 * 264];
  int y = blockIdx.y;
  const float* A = y ? A1 : A0;
  short* Cb = y ? Cb1 : Cb0;
  const short* Wp = Wb + y * 65536;
  const float* bp = bias + y * 256;
  int t = threadIdx.x;
  int m0 = blockIdx.x * 32;
  int wave = t >> 6, lane = t & 63, r = lane & 15, g = lane >> 4;

  {
    int row = t >> 3, c0 = (t & 7) * 32;
    const float* ap = A + ((size_t)m0 + row) * 256 + c0;
    float4 ld[8];
#pragma unroll
    for (int j = 0; j < 8; ++j) ld[j] = *(const float4*)(ap + j * 4);
    short* dst = &As[row * 264 + c0];
#pragma unroll
    for (int j = 0; j < 4; ++j)
      *(short8v*)(dst + j * 8) = pack8(ld[2 * j], ld[2 * j + 1]);
  }
  __syncthreads();

  f32x4 acc[2][4] = {};
  const short* wbase = Wp + (size_t)(wave * 64 + r) * 256;
#pragma unroll
  for (int ks = 0; ks < 8; ++ks) {
    short8v af0 = *(const short8v*)&As[r * 264 + ks * 32 + g * 8];
    short8v af1 = *(const short8v*)&As[(16 + r) * 264 + ks * 32 + g * 8];
    short8v bf[4];
#pragma unroll
    for (int nf = 0; nf < 4; ++nf)
      bf[nf] = *(const short8v*)(wbase + nf * 16 * 256 + ks * 32 + g * 8);
#pragma unroll
    for (int nf = 0; nf < 4; ++nf) {
      acc[0][nf] = __builtin_amdgcn_mfma_f32_16x16x32_bf16(af0, bf[nf], acc[0][nf], 0, 0, 0);
      acc[1][nf] = __builtin_amdgcn_mfma_f32_16x16x32_bf16(af1, bf[nf], acc[1][nf], 0, 0, 0);
    }
  }

#pragma unroll
  for (int mf = 0; mf < 2; ++mf)
#pragma unroll
    for (int nf = 0; nf < 4; ++nf) {
      int nn = wave * 64 + nf * 16 + r;
      float bval = bp[nn];
#pragma unroll
      for (int i = 0; i < 4; ++i) {
        int m = m0 + mf * 16 + g * 4 + i;
        float val = (acc[mf][nf][i] + bval) * scale;
        if (mode == 1) {
          int bb = m / 300, ll = m - bb * 300;
          Cf[((size_t)ll * 8 + bb) * 256 + nn] = val;
        } else {  // mode 3
          Cb[(size_t)m * 256 + nn] = (short)f2bf(val);
        }
      }
    }
}

// ---------------- value projection v10 ----------------
// vvT[bn][d(32)][hw(9216)] bf16. grid 256 x 512 thr (8 waves x 32 channels);
// 288 rows/block (18 tiles of 16). 2 waves/SIMD hides LDS latency; B traffic
// per block unchanged (each wave 64 VGPR of frags, "+a" pinned). Depth-2 GLL
// pipeline, counted vmcnt; 4-tile store groups (full-line writes).
__global__ __launch_bounds__(512, 1) void vproj_kernel(
    const float* __restrict__ A, const short* __restrict__ Wb,
    const float* __restrict__ bias, short* __restrict__ vvT) {
  __shared__ float buf[2][16 * 260];   // 33.3 KB
  __shared__ short Ts[8][32 * 68];     // per-wave 32ch x (64hw pad68) = 34.8 KB
  int t = threadIdx.x;
  int wave = t >> 6, lane = t & 63, r = lane & 15, g = lane >> 4;
  int m0g = blockIdx.x * 288;
  int b_ = blockIdx.x >> 5;            // 32 blocks per batch
  int hw00 = (blockIdx.x & 31) * 288;
  int chbase = wave * 32;

  // hoist B (wave's 32 output channels, full K = 16 frags = 64 regs), pin
  short8v bf[8][2];
  {
    const short* wbase = Wb + (size_t)(chbase + r) * 256;
#pragma unroll
    for (int ks = 0; ks < 8; ++ks)
#pragma unroll
      for (int nf = 0; nf < 2; ++nf)
        bf[ks][nf] = *(const short8v*)(wbase + nf * 16 * 256 + ks * 32 + g * 8);
  }
#pragma unroll
  for (int ks = 0; ks < 8; ++ks)
#pragma unroll
    for (int nf = 0; nf < 2; ++nf)
      asm volatile("" : "+a"(bf[ks][nf]));
  float bias_v[2];
#pragma unroll
  for (int nf = 0; nf < 2; ++nf) bias_v[nf] = bias[chbase + nf * 16 + r];

  // prologue: stage tiles 0,1; wave stages rows wave*2, wave*2+1 of each
#pragma unroll
  for (int q = 0; q < 2; ++q) {
#pragma unroll
    for (int i = 0; i < 2; ++i) {
      int row = wave * 2 + i;
      const float* gp = A + ((size_t)m0g + q * 16 + row) * 256 + lane * 4;
      GLL16(gp, &buf[q][row * 260]);
    }
  }

  int chg = chbase + (lane & 31);      // lane's output channel
  int half = lane >> 5;
  short* vbase = vvT + (size_t)(b_ * 8 + (chg >> 5)) * 294912 +
                 (size_t)(chg & 31) * 9216 + hw00;
  const short* tsr = &Ts[wave][(lane & 31) * 68];

#pragma unroll
  for (int tt = 0; tt < 18; ++tt) {
    // counted wait for tile tt's 2 GLLs (per-wave vmcnt, in-order retirement)
    if (tt == 17)                 asm volatile("s_waitcnt vmcnt(0)" ::: "memory");
    else if (tt && (tt & 3) == 0) asm volatile("s_waitcnt vmcnt(6)" ::: "memory");
    else                          asm volatile("s_waitcnt vmcnt(2)" ::: "memory");
    __builtin_amdgcn_s_barrier();

    // compute tile tt from buf[tt&1]: 8 ks x 2 nf MFMAs
    f32x4 acc[2] = {};
    const float* bp_ = &buf[tt & 1][0];
#pragma unroll
    for (int ks = 0; ks < 8; ++ks) {
      const float* p = bp_ + r * 260 + ks * 32 + g * 8;
      f32x4 lo = *(const f32x4*)p;
      f32x4 hi = *(const f32x4*)(p + 4);
      short8v af = pack8cvt(lo, hi);
      acc[0] = __builtin_amdgcn_mfma_f32_16x16x32_bf16(af, bf[ks][0], acc[0], 0, 0, 0);
      acc[1] = __builtin_amdgcn_mfma_f32_16x16x32_bf16(af, bf[ks][1], acc[1], 0, 0, 0);
    }

    // Ts transpose slot (tt&3)*16 (wave-private; DS in-order per wave)
#pragma unroll
    for (int nf = 0; nf < 2; ++nf) {
      float bv = bias_v[nf];
      *(short4v*)&Ts[wave][(nf * 16 + r) * 68 + (tt & 3) * 16 + g * 4] =
          pack4cvt(acc[nf][0] + bv, acc[nf][1] + bv, acc[nf][2] + bv, acc[nf][3] + bv);
    }
    asm volatile("" ::: "memory");

    // store group every 4 tiles: 64 hw/channel; lane stores its half (64B)
    if ((tt & 3) == 3) {
      short* gdst = vbase + (tt >> 2) * 64 + half * 32;
      const short* src = tsr + half * 32;
#pragma unroll
      for (int j = 0; j < 4; ++j)
        *(short8v*)(gdst + j * 8) = *(const short8v*)(src + j * 8);
      asm volatile("" ::: "memory");
    } else if (tt == 17) {  // final partial group: tiles 16,17 -> 32 hw
      short* gdst = vbase + 256 + half * 16;
      const short* src = tsr + half * 16;
#pragma unroll
      for (int j = 0; j < 2; ++j)
        *(short8v*)(gdst + j * 8) = *(const short8v*)(src + j * 8);
      asm volatile("" ::: "memory");
    }

    __builtin_amdgcn_s_barrier();  // all waves done reading buf[tt&1]
    if (tt + 2 < 18) {             // refill with tile tt+2
#pragma unroll
      for (int i = 0; i < 2; ++i) {
        int row = wave * 2 + i;
        const float* gp = A + ((size_t)m0g + (tt + 2) * 16 + row) * 256 + lane * 4;
        GLL16(gp, &buf[tt & 1][row * 260]);
      }
    }
  }
}

// ---------------- scores + softmax: MFMA + in-register softmax ----------------
__global__ __launch_bounds__(64) void scores_softmax_v2(
    const short* __restrict__ qrb, const short* __restrict__ qcb,
    const short* __restrict__ krb, const short* __restrict__ kcb,
    short* __restrict__ wrowB, float* __restrict__ wcolT) {
  int lchunk = blockIdx.x, bn = blockIdx.y, kind = blockIdx.z;
  int b = bn >> 3, n = bn & 7;
  int lane = threadIdx.x;
  int r = lane & 15, g = lane >> 4;
  const short* qb = kind ? qcb : qrb;
  const short* kb = kind ? kcb : krb;
  int l0 = lchunk * 80;

  short8v a[5], bfr[6];
#pragma unroll
  for (int lf = 0; lf < 5; ++lf) {
    int l = l0 + lf * 16 + r;
    if (l > 299) l = 299;
    a[lf] = *(const short8v*)(qb + ((size_t)b * 300 + l) * 256 + n * 32 + g * 8);
  }
#pragma unroll
  for (int f = 0; f < 6; ++f)
    bfr[f] = *(const short8v*)(kb + ((size_t)b * 96 + f * 16 + r) * 256 + n * 32 + g * 8);

  f32x4 c[5][6];
#pragma unroll
  for (int lf = 0; lf < 5; ++lf)
#pragma unroll
    for (int f = 0; f < 6; ++f) {
      f32x4 z = {};
      c[lf][f] = __builtin_amdgcn_mfma_f32_16x16x32_bf16(a[lf], bfr[f], z, 0, 0, 0);
    }

#pragma unroll
  for (int lf = 0; lf < 5; ++lf)
#pragma unroll
    for (int i = 0; i < 4; ++i) {
      float m = c[lf][0][i];
#pragma unroll
      for (int f = 1; f < 6; ++f) m = fmaxf(m, c[lf][f][i]);
#pragma unroll
      for (int mask = 1; mask <= 8; mask <<= 1) m = fmaxf(m, __shfl_xor(m, mask, 64));
      float e[6], s = 0.f;
#pragma unroll
      for (int f = 0; f < 6; ++f) { e[f] = __expf(c[lf][f][i] - m); s += e[f]; }
#pragma unroll
      for (int mask = 1; mask <= 8; mask <<= 1) s += __shfl_xor(s, mask, 64);
      float inv = 1.f / s;
#pragma unroll
      for (int f = 0; f < 6; ++f) c[lf][f][i] = e[f] * inv;
    }

  if (kind == 0) {
#pragma unroll
    for (int lf = 0; lf < 5; ++lf)
#pragma unroll
      for (int i = 0; i < 4; ++i) {
        int l = l0 + lf * 16 + g * 4 + i;
        bool ok = (l < 300);
#pragma unroll
        for (int f = 0; f < 6; ++f) {
          float wv = ok ? c[lf][f][i] : 0.f;
          wrowB[((size_t)bn * 320 + l) * 96 + f * 16 + r] = (short)f2bf(wv);
        }
      }
  } else {
#pragma unroll
    for (int lf = 0; lf < 5; ++lf)
#pragma unroll
      for (int f = 0; f < 6; ++f) {
        int l = l0 + lf * 16 + g * 4;
        f32x4 wv = c[lf][f];
#pragma unroll
        for (int i = 0; i < 4; ++i) if (l + i >= 300) wv[i] = 0.f;
        *(f32x4*)(wcolT + ((size_t)bn * 96 + f * 16 + r) * 320 + l) = wv;
      }
  }
}

// ---------------- fused bilinear attention (MFMA, 8 waves, XCD swizzle) ----
// linear grid 320; decode keeps all 5 lh-blocks of a bn on one XCD's L2.
__global__ __launch_bounds__(512) void attn_kernel(
    const short* __restrict__ wrowB, const float* __restrict__ wcolT,
    const short* __restrict__ vvT, float* __restrict__ ao) {
  __shared__ f32x4 cmb[3][2][4][64];
  int i = blockIdx.x;
  int xcd = i & 7, j = i >> 3;
  int bn = (j / 5) * 8 + xcd;
  int lh = j - (j / 5) * 5;
  int b = bn >> 3, n = bn & 7;
  int t = threadIdx.x, wave = t >> 6, lane = t & 63;
  int df = wave & 1, hh = wave >> 1;
  int lbase = lh * 64;
  int r = lane & 15, g = lane >> 4;

  short8v a[4][3];
  const short* wr = wrowB + (size_t)bn * 320 * 96;
#pragma unroll
  for (int lf = 0; lf < 4; ++lf)
#pragma unroll
    for (int ks = 0; ks < 3; ++ks)
      a[lf][ks] = *(const short8v*)(wr + (lbase + lf * 16 + r) * 96 + ks * 32 + g * 8);

  const short* vb = vvT + (size_t)bn * 294912 + (size_t)(df * 16 + r) * 9216 + hh * 24 * 96;
  const float* wcb = wcolT + ((size_t)bn * 96 + hh * 24) * 320 + lbase + g * 4;

  f32x4 acc[4] = {};
  short8v b0[3], b1[3];
  f32x4 w0[4], w1[4];
#pragma unroll
  for (int ks = 0; ks < 3; ++ks) b0[ks] = *(const short8v*)(vb + ks * 32 + g * 8);
#pragma unroll
  for (int lf = 0; lf < 4; ++lf) w0[lf] = *(const f32x4*)(wcb + lf * 16);

  for (int h2 = 0; h2 < 12; ++h2) {
    int h = h2 * 2;
#pragma unroll
    for (int ks = 0; ks < 3; ++ks) b1[ks] = *(const short8v*)(vb + (h + 1) * 96 + ks * 32 + g * 8);
#pragma unroll
    for (int lf = 0; lf < 4; ++lf) w1[lf] = *(const f32x4*)(wcb + (h + 1) * 320 + lf * 16);
    {
      f32x4 R[4] = {};
#pragma unroll
      for (int ks = 0; ks < 3; ++ks)
#pragma unroll
        for (int lf = 0; lf < 4; ++lf)
          R[lf] = __builtin_amdgcn_mfma_f32_16x16x32_bf16(a[lf][ks], b0[ks], R[lf], 0, 0, 0);
#pragma unroll
      for (int lf = 0; lf < 4; ++lf) acc[lf] += w0[lf] * R[lf];
    }
    if (h2 < 11) {
#pragma unroll
      for (int ks = 0; ks < 3; ++ks) b0[ks] = *(const short8v*)(vb + (h + 2) * 96 + ks * 32 + g * 8);
#pragma unroll
      for (int lf = 0; lf < 4; ++lf) w0[lf] = *(const f32x4*)(wcb + (h + 2) * 320 + lf * 16);
    }
    {
      f32x4 R[4] = {};
#pragma unroll
      for (int ks = 0; ks < 3; ++ks)
#pragma unroll
        for (int lf = 0; lf < 4; ++lf)
          R[lf] = __builtin_amdgcn_mfma_f32_16x16x32_bf16(a[lf][ks], b1[ks], R[lf], 0, 0, 0);
#pragma unroll
      for (int lf = 0; lf < 4; ++lf) acc[lf] += w1[lf] * R[lf];
    }
  }

  if (hh > 0) {
#pragma unroll
    for (int lf = 0; lf < 4; ++lf) cmb[hh - 1][df][lf][lane] = acc[lf];
  }
  __syncthreads();
  if (hh == 0) {
#pragma unroll
    for (int lf = 0; lf < 4; ++lf) {
      f32x4 o = acc[lf];
#pragma unroll
      for (int q = 0; q < 3; ++q) o += cmb[q][df][lf][lane];
#pragma unroll
      for (int i2 = 0; i2 < 4; ++i2) {
        int l = lbase + lf * 16 + g * 4 + i2;
        if (l < 300)
          ao[((size_t)b * 300 + l) * 256 + n * 32 + df * 16 + r] = o[i2];
      }
    }
  }
}

// ---------------- launch ----------------
extern "C" void kernel_launch(void* const* d_in, const int* in_sizes, int n_in,
                              void* d_out, int out_size, void* d_ws, size_t ws_size,
                              hipStream_t stream) {
  const float* query_row = (const float*)d_in[0];
  const float* query_col = (const float*)d_in[1];
  const float* key_row   = (const float*)d_in[2];
  const float* key_col   = (const float*)d_in[3];
  const float* value     = (const float*)d_in[4];
  const float* W         = (const float*)d_in[5];  // (1280,256)
  const float* Bv        = (const float*)d_in[6];  // (1280,)
  const float* Wout      = (const float*)d_in[7];  // (256,256)
  const float* Bout      = (const float*)d_in[8];  // (256,)

  float* ws = (float*)d_ws;
  float* krm   = ws;                        // 196608 f
  float* kcm   = krm + 196608;              // 196608 f
  float* ao    = kcm + 196608;              // 614400 f
  float* wcolT = ao + 614400;               // 1966080 f
  short* qrb   = (short*)(wcolT + 1966080); // 614400 s
  short* qcb   = qrb + 614400;              // 614400 s
  short* krb   = qcb + 614400;              // 196608 s
  short* kcb   = krb + 196608;              // 196608 s
  short* wrowB = kcb + 196608;              // 1966080 s
  short* vvT   = wrowB + 1966080;           // 18874368 s
  short* Wb    = vvT + 18874368;            // 393216 s

  cvt_w_kernel<<<1536, 256, 0, stream>>>(W, Wout, Wb);
  mean_over_h_v3<<<768, 256, 0, stream>>>(key_row, krm);
  mean_over_w_v3<<<768, 256, 0, stream>>>(key_col, kcm);
  gemm_proj<<<dim3(75, 2), 256, 0, stream>>>(query_row, query_col, Wb, Bv,
                                             nullptr, qrb, qcb, SCALE_Q, 3);
  gemm_proj<<<dim3(24, 2), 256, 0, stream>>>(krm, kcm, Wb + 131072, Bv + 512,
                                             nullptr, krb, kcb, 1.f, 3);
  vproj_kernel<<<256, 512, 0, stream>>>(value, Wb + 262144, Bv + 1024, vvT);
  scores_softmax_v2<<<dim3(4, 64, 2), 64, 0, stream>>>(qrb, qcb, krb, kcb, wrowB, wcolT);
  attn_kernel<<<320, 512, 0, stream>>>(wrowB, wcolT, vvT, ao);
  gemm_proj<<<dim3(75, 1), 256, 0, stream>>>(ao, nullptr, Wb + 327680, Bout,
                                             (float*)d_out, nullptr, nullptr, 1.f, 1);
}

// Round 13
// 157.634 us; speedup vs baseline: 1.0182x; 1.0122x over previous
//
#include <hip/hip_runtime.h>
#include <cstdint>

// MultiheadRCDA: N=8, L=300, HH=WW=96, E=256, NH=8, HD=32
// Round 13: attn depth-4 register ring (r12 proved latency-bound: FETCH fixed
// 98->24.9MB but dur unchanged; in-flight was 1 h-step = 112B/wave). Prefetch
// distance now 3 compute steps (~250cy). Everything else unchanged.

typedef __attribute__((ext_vector_type(8))) short short8v;  // bf16x8 MFMA frag
typedef __attribute__((ext_vector_type(4))) short short4v;  // 8B packed bf16
typedef __attribute__((ext_vector_type(4))) float f32x4;

#define SCALE_Q 0.17677669529663687f  // 32^-0.5

#define GLL16(gp, lp)                                                   \
  __builtin_amdgcn_global_load_lds(                                     \
      (const __attribute__((address_space(1))) void*)(gp),              \
      (__attribute__((address_space(3))) void*)(lp), 16, 0, 0)

__device__ __forceinline__ unsigned short f2bf(float x) {
  unsigned int u = __builtin_bit_cast(unsigned int, x);
  u += 0x7FFFu + ((u >> 16) & 1u);
  return (unsigned short)(u >> 16);
}

__device__ __forceinline__ unsigned int cvtpk(float a, float b) {
  unsigned int r;
  asm("v_cvt_pk_bf16_f32 %0, %1, %2" : "=v"(r) : "v"(a), "v"(b));
  return r;
}

__device__ __forceinline__ short8v pack8cvt(const f32x4& lo, const f32x4& hi) {
  union { short8v s; unsigned int u[4]; } z;
  z.u[0] = cvtpk(lo[0], lo[1]);
  z.u[1] = cvtpk(lo[2], lo[3]);
  z.u[2] = cvtpk(hi[0], hi[1]);
  z.u[3] = cvtpk(hi[2], hi[3]);
  return z.s;
}

__device__ __forceinline__ short4v pack4cvt(float a, float b, float c, float d) {
  union { short4v s; unsigned int u[2]; } z;
  z.u[0] = cvtpk(a, b);
  z.u[1] = cvtpk(c, d);
  return z.s;
}

__device__ __forceinline__ short8v pack8(const float4& fa, const float4& fb) {
  short8v v;
  v[0] = (short)f2bf(fa.x); v[1] = (short)f2bf(fa.y);
  v[2] = (short)f2bf(fa.z); v[3] = (short)f2bf(fa.w);
  v[4] = (short)f2bf(fb.x); v[5] = (short)f2bf(fb.y);
  v[6] = (short)f2bf(fb.z); v[7] = (short)f2bf(fb.w);
  return v;
}

// ---------------- weight fp32->bf16 ----------------
__global__ __launch_bounds__(256) void cvt_w_kernel(const float* __restrict__ w_in,
                                                    const float* __restrict__ w_out,
                                                    short* __restrict__ Wb) {
  int idx = blockIdx.x * 256 + threadIdx.x;  // 393216 total
  float v = (idx < 327680) ? w_in[idx] : w_out[idx - 327680];
  Wb[idx] = (short)f2bf(v);
}

// ---------------- mean kernels v3 ----------------
__global__ __launch_bounds__(256) void mean_over_h_v3(const float* __restrict__ in,
                                                      float* __restrict__ out) {
  __shared__ float4 part[256];
  int bw = blockIdx.x;  // b*96 + w
  int b = bw / 96, w = bw - b * 96;
  int t = threadIdx.x, e4 = t & 63, hq = t >> 6;
  const float4* p = (const float4*)(in + ((size_t)b * 9216 + w) * 256) + e4 +
                    (size_t)hq * 24 * 6144;
  float4 s = {0.f, 0.f, 0.f, 0.f};
#pragma unroll
  for (int i = 0; i < 24; ++i) {
    float4 v = p[(size_t)i * 6144];
    s.x += v.x; s.y += v.y; s.z += v.z; s.w += v.w;
  }
  part[t] = s;
  __syncthreads();
  if (t < 64) {
    float4 a = part[t], c = part[t + 64], d = part[t + 128], e = part[t + 192];
    float4 o;
    o.x = (a.x + c.x + d.x + e.x) * (1.f / 96.f);
    o.y = (a.y + c.y + d.y + e.y) * (1.f / 96.f);
    o.z = (a.z + c.z + d.z + e.z) * (1.f / 96.f);
    o.w = (a.w + c.w + d.w + e.w) * (1.f / 96.f);
    ((float4*)out)[(size_t)bw * 64 + t] = o;
  }
}

__global__ __launch_bounds__(256) void mean_over_w_v3(const float* __restrict__ in,
                                                      float* __restrict__ out) {
  __shared__ float4 part[256];
  int bh = blockIdx.x;  // b*96 + h
  int t = threadIdx.x, e4 = t & 63, wq = t >> 6;
  const float4* p = (const float4*)(in + (size_t)bh * 24576) + e4 + (size_t)wq * 24 * 64;
  float4 s = {0.f, 0.f, 0.f, 0.f};
#pragma unroll
  for (int i = 0; i < 24; ++i) {
    float4 v = p[(size_t)i * 64];
    s.x += v.x; s.y += v.y; s.z += v.z; s.w += v.w;
  }
  part[t] = s;
  __syncthreads();
  if (t < 64) {
    float4 a = part[t], c = part[t + 64], d = part[t + 128], e = part[t + 192];
    float4 o;
    o.x = (a.x + c.x + d.x + e.x) * (1.f / 96.f);
    o.y = (a.y + c.y + d.y + e.y) * (1.f / 96.f);
    o.z = (a.z + c.z + d.z + e.z) * (1.f / 96.f);
    o.w = (a.w + c.w + d.w + e.w) * (1.f / 96.f);
    ((float4*)out)[(size_t)bh * 64 + t] = o;
  }
}

// ---------------- bf16 MFMA projection GEMM (q/k/out), BM=32 ----------------
__global__ __launch_bounds__(256) void gemm_proj(
    const float* __restrict__ A0, const float* __restrict__ A1,
    const short* __restrict__ Wb, const float* __restrict__ bias,
    float* __restrict__ Cf, short* __restrict__ Cb0, short* __restrict__ Cb1,
    float scale, int mode) {
  __shared__ short As[32 * 264];
  int y = blockIdx.y;
  const float* A = y ? A1 : A0;
  short* Cb = y ? Cb1 : Cb0;
  const short* Wp = Wb + y * 65536;
  const float* bp = bias + y * 256;
  int t = threadIdx.x;
  int m0 = blockIdx.x * 32;
  int wave = t >> 6, lane = t & 63, r = lane & 15, g = lane >> 4;

  {
    int row = t >> 3, c0 = (t & 7) * 32;
    const float* ap = A + ((size_t)m0 + row) * 256 + c0;
    float4 ld[8];
#pragma unroll
    for (int j = 0; j < 8; ++j) ld[j] = *(const float4*)(ap + j * 4);
    short* dst = &As[row * 264 + c0];
#pragma unroll
    for (int j = 0; j < 4; ++j)
      *(short8v*)(dst + j * 8) = pack8(ld[2 * j], ld[2 * j + 1]);
  }
  __syncthreads();

  f32x4 acc[2][4] = {};
  const short* wbase = Wp + (size_t)(wave * 64 + r) * 256;
#pragma unroll
  for (int ks = 0; ks < 8; ++ks) {
    short8v af0 = *(const short8v*)&As[r * 264 + ks * 32 + g * 8];
    short8v af1 = *(const short8v*)&As[(16 + r) * 264 + ks * 32 + g * 8];
    short8v bf[4];
#pragma unroll
    for (int nf = 0; nf < 4; ++nf)
      bf[nf] = *(const short8v*)(wbase + nf * 16 * 256 + ks * 32 + g * 8);
#pragma unroll
    for (int nf = 0; nf < 4; ++nf) {
      acc[0][nf] = __builtin_amdgcn_mfma_f32_16x16x32_bf16(af0, bf[nf], acc[0][nf], 0, 0, 0);
      acc[1][nf] = __builtin_amdgcn_mfma_f32_16x16x32_bf16(af1, bf[nf], acc[1][nf], 0, 0, 0);
    }
  }

#pragma unroll
  for (int mf = 0; mf < 2; ++mf)
#pragma unroll
    for (int nf = 0; nf < 4; ++nf) {
      int nn = wave * 64 + nf * 16 + r;
      float bval = bp[nn];
#pragma unroll
      for (int i = 0; i < 4; ++i) {
        int m = m0 + mf * 16 + g * 4 + i;
        float val = (acc[mf][nf][i] + bval) * scale;
        if (mode == 1) {
          int bb = m / 300, ll = m - bb * 300;
          Cf[((size_t)ll * 8 + bb) * 256 + nn] = val;
        } else {  // mode 3
          Cb[(size_t)m * 256 + nn] = (short)f2bf(val);
        }
      }
    }
}

// ---------------- value projection v10 (unchanged from r12) ----------------
__global__ __launch_bounds__(512, 1) void vproj_kernel(
    const float* __restrict__ A, const short* __restrict__ Wb,
    const float* __restrict__ bias, short* __restrict__ vvT) {
  __shared__ float buf[2][16 * 260];
  __shared__ short Ts[8][32 * 68];
  int t = threadIdx.x;
  int wave = t >> 6, lane = t & 63, r = lane & 15, g = lane >> 4;
  int m0g = blockIdx.x * 288;
  int b_ = blockIdx.x >> 5;
  int hw00 = (blockIdx.x & 31) * 288;
  int chbase = wave * 32;

  short8v bf[8][2];
  {
    const short* wbase = Wb + (size_t)(chbase + r) * 256;
#pragma unroll
    for (int ks = 0; ks < 8; ++ks)
#pragma unroll
      for (int nf = 0; nf < 2; ++nf)
        bf[ks][nf] = *(const short8v*)(wbase + nf * 16 * 256 + ks * 32 + g * 8);
  }
#pragma unroll
  for (int ks = 0; ks < 8; ++ks)
#pragma unroll
    for (int nf = 0; nf < 2; ++nf)
      asm volatile("" : "+a"(bf[ks][nf]));
  float bias_v[2];
#pragma unroll
  for (int nf = 0; nf < 2; ++nf) bias_v[nf] = bias[chbase + nf * 16 + r];

#pragma unroll
  for (int q = 0; q < 2; ++q) {
#pragma unroll
    for (int i = 0; i < 2; ++i) {
      int row = wave * 2 + i;
      const float* gp = A + ((size_t)m0g + q * 16 + row) * 256 + lane * 4;
      GLL16(gp, &buf[q][row * 260]);
    }
  }

  int chg = chbase + (lane & 31);
  int half = lane >> 5;
  short* vbase = vvT + (size_t)(b_ * 8 + (chg >> 5)) * 294912 +
                 (size_t)(chg & 31) * 9216 + hw00;
  const short* tsr = &Ts[wave][(lane & 31) * 68];

#pragma unroll
  for (int tt = 0; tt < 18; ++tt) {
    if (tt == 17)                 asm volatile("s_waitcnt vmcnt(0)" ::: "memory");
    else if (tt && (tt & 3) == 0) asm volatile("s_waitcnt vmcnt(6)" ::: "memory");
    else                          asm volatile("s_waitcnt vmcnt(2)" ::: "memory");
    __builtin_amdgcn_s_barrier();

    f32x4 acc[2] = {};
    const float* bp_ = &buf[tt & 1][0];
#pragma unroll
    for (int ks = 0; ks < 8; ++ks) {
      const float* p = bp_ + r * 260 + ks * 32 + g * 8;
      f32x4 lo = *(const f32x4*)p;
      f32x4 hi = *(const f32x4*)(p + 4);
      short8v af = pack8cvt(lo, hi);
      acc[0] = __builtin_amdgcn_mfma_f32_16x16x32_bf16(af, bf[ks][0], acc[0], 0, 0, 0);
      acc[1] = __builtin_amdgcn_mfma_f32_16x16x32_bf16(af, bf[ks][1], acc[1], 0, 0, 0);
    }

#pragma unroll
    for (int nf = 0; nf < 2; ++nf) {
      float bv = bias_v[nf];
      *(short4v*)&Ts[wave][(nf * 16 + r) * 68 + (tt & 3) * 16 + g * 4] =
          pack4cvt(acc[nf][0] + bv, acc[nf][1] + bv, acc[nf][2] + bv, acc[nf][3] + bv);
    }
    asm volatile("" ::: "memory");

    if ((tt & 3) == 3) {
      short* gdst = vbase + (tt >> 2) * 64 + half * 32;
      const short* src = tsr + half * 32;
#pragma unroll
      for (int j = 0; j < 4; ++j)
        *(short8v*)(gdst + j * 8) = *(const short8v*)(src + j * 8);
      asm volatile("" ::: "memory");
    } else if (tt == 17) {
      short* gdst = vbase + 256 + half * 16;
      const short* src = tsr + half * 16;
#pragma unroll
      for (int j = 0; j < 2; ++j)
        *(short8v*)(gdst + j * 8) = *(const short8v*)(src + j * 8);
      asm volatile("" ::: "memory");
    }

    __builtin_amdgcn_s_barrier();
    if (tt + 2 < 18) {
#pragma unroll
      for (int i = 0; i < 2; ++i) {
        int row = wave * 2 + i;
        const float* gp = A + ((size_t)m0g + (tt + 2) * 16 + row) * 256 + lane * 4;
        GLL16(gp, &buf[tt & 1][row * 260]);
      }
    }
  }
}

// ---------------- scores + softmax: MFMA + in-register softmax ----------------
__global__ __launch_bounds__(64) void scores_softmax_v2(
    const short* __restrict__ qrb, const short* __restrict__ qcb,
    const short* __restrict__ krb, const short* __restrict__ kcb,
    short* __restrict__ wrowB, float* __restrict__ wcolT) {
  int lchunk = blockIdx.x, bn = blockIdx.y, kind = blockIdx.z;
  int b = bn >> 3, n = bn & 7;
  int lane = threadIdx.x;
  int r = lane & 15, g = lane >> 4;
  const short* qb = kind ? qcb : qrb;
  const short* kb = kind ? kcb : krb;
  int l0 = lchunk * 80;

  short8v a[5], bfr[6];
#pragma unroll
  for (int lf = 0; lf < 5; ++lf) {
    int l = l0 + lf * 16 + r;
    if (l > 299) l = 299;
    a[lf] = *(const short8v*)(qb + ((size_t)b * 300 + l) * 256 + n * 32 + g * 8);
  }
#pragma unroll
  for (int f = 0; f < 6; ++f)
    bfr[f] = *(const short8v*)(kb + ((size_t)b * 96 + f * 16 + r) * 256 + n * 32 + g * 8);

  f32x4 c[5][6];
#pragma unroll
  for (int lf = 0; lf < 5; ++lf)
#pragma unroll
    for (int f = 0; f < 6; ++f) {
      f32x4 z = {};
      c[lf][f] = __builtin_amdgcn_mfma_f32_16x16x32_bf16(a[lf], bfr[f], z, 0, 0, 0);
    }

#pragma unroll
  for (int lf = 0; lf < 5; ++lf)
#pragma unroll
    for (int i = 0; i < 4; ++i) {
      float m = c[lf][0][i];
#pragma unroll
      for (int f = 1; f < 6; ++f) m = fmaxf(m, c[lf][f][i]);
#pragma unroll
      for (int mask = 1; mask <= 8; mask <<= 1) m = fmaxf(m, __shfl_xor(m, mask, 64));
      float e[6], s = 0.f;
#pragma unroll
      for (int f = 0; f < 6; ++f) { e[f] = __expf(c[lf][f][i] - m); s += e[f]; }
#pragma unroll
      for (int mask = 1; mask <= 8; mask <<= 1) s += __shfl_xor(s, mask, 64);
      float inv = 1.f / s;
#pragma unroll
      for (int f = 0; f < 6; ++f) c[lf][f][i] = e[f] * inv;
    }

  if (kind == 0) {
#pragma unroll
    for (int lf = 0; lf < 5; ++lf)
#pragma unroll
      for (int i = 0; i < 4; ++i) {
        int l = l0 + lf * 16 + g * 4 + i;
        bool ok = (l < 300);
#pragma unroll
        for (int f = 0; f < 6; ++f) {
          float wv = ok ? c[lf][f][i] : 0.f;
          wrowB[((size_t)bn * 320 + l) * 96 + f * 16 + r] = (short)f2bf(wv);
        }
      }
  } else {
#pragma unroll
    for (int lf = 0; lf < 5; ++lf)
#pragma unroll
      for (int f = 0; f < 6; ++f) {
        int l = l0 + lf * 16 + g * 4;
        f32x4 wv = c[lf][f];
#pragma unroll
        for (int i = 0; i < 4; ++i) if (l + i >= 300) wv[i] = 0.f;
        *(f32x4*)(wcolT + ((size_t)bn * 96 + f * 16 + r) * 320 + l) = wv;
      }
  }
}

// ---------------- fused bilinear attention (depth-4 ring, XCD swizzle) ----
__global__ __launch_bounds__(512, 2) void attn_kernel(
    const short* __restrict__ wrowB, const float* __restrict__ wcolT,
    const short* __restrict__ vvT, float* __restrict__ ao) {
  __shared__ f32x4 cmb[3][2][4][64];
  int i = blockIdx.x;
  int xcd = i & 7, j = i >> 3;
  int bn = (j / 5) * 8 + xcd;
  int lh = j - (j / 5) * 5;
  int b = bn >> 3, n = bn & 7;
  int t = threadIdx.x, wave = t >> 6, lane = t & 63;
  int df = wave & 1, hh = wave >> 1;
  int lbase = lh * 64;
  int r = lane & 15, g = lane >> 4;

  short8v a[4][3];
  const short* wr = wrowB + (size_t)bn * 320 * 96;
#pragma unroll
  for (int lf = 0; lf < 4; ++lf)
#pragma unroll
    for (int ks = 0; ks < 3; ++ks)
      a[lf][ks] = *(const short8v*)(wr + (lbase + lf * 16 + r) * 96 + ks * 32 + g * 8);

  const short* vb = vvT + (size_t)bn * 294912 + (size_t)(df * 16 + r) * 9216 + hh * 24 * 96;
  const float* wcb = wcolT + ((size_t)bn * 96 + hh * 24) * 320 + lbase + g * 4;

  f32x4 acc[4] = {};
  short8v bR[4][3];
  f32x4 wR[4][4];
  // prologue: fill 4-deep ring (h-steps 0..3)
#pragma unroll
  for (int q = 0; q < 4; ++q) {
#pragma unroll
    for (int ks = 0; ks < 3; ++ks)
      bR[q][ks] = *(const short8v*)(vb + q * 96 + ks * 32 + g * 8);
#pragma unroll
    for (int lf = 0; lf < 4; ++lf)
      wR[q][lf] = *(const f32x4*)(wcb + q * 320 + lf * 16);
  }

#pragma unroll
  for (int hs = 0; hs < 24; ++hs) {
    int cur = hs & 3;  // compile-time after full unroll (rule #20 safe)
    f32x4 R[4] = {};
#pragma unroll
    for (int ks = 0; ks < 3; ++ks)
#pragma unroll
      for (int lf = 0; lf < 4; ++lf)
        R[lf] = __builtin_amdgcn_mfma_f32_16x16x32_bf16(a[lf][ks], bR[cur][ks], R[lf], 0, 0, 0);
#pragma unroll
    for (int lf = 0; lf < 4; ++lf) acc[lf] += wR[cur][lf] * R[lf];
    if (hs + 4 < 24) {  // refill freed slot with h-step hs+4
#pragma unroll
      for (int ks = 0; ks < 3; ++ks)
        bR[cur][ks] = *(const short8v*)(vb + (hs + 4) * 96 + ks * 32 + g * 8);
#pragma unroll
      for (int lf = 0; lf < 4; ++lf)
        wR[cur][lf] = *(const f32x4*)(wcb + (hs + 4) * 320 + lf * 16);
    }
  }

  if (hh > 0) {
#pragma unroll
    for (int lf = 0; lf < 4; ++lf) cmb[hh - 1][df][lf][lane] = acc[lf];
  }
  __syncthreads();
  if (hh == 0) {
#pragma unroll
    for (int lf = 0; lf < 4; ++lf) {
      f32x4 o = acc[lf];
#pragma unroll
      for (int q = 0; q < 3; ++q) o += cmb[q][df][lf][lane];
#pragma unroll
      for (int i2 = 0; i2 < 4; ++i2) {
        int l = lbase + lf * 16 + g * 4 + i2;
        if (l < 300)
          ao[((size_t)b * 300 + l) * 256 + n * 32 + df * 16 + r] = o[i2];
      }
    }
  }
}

// ---------------- launch ----------------
extern "C" void kernel_launch(void* const* d_in, const int* in_sizes, int n_in,
                              void* d_out, int out_size, void* d_ws, size_t ws_size,
                              hipStream_t stream) {
  const float* query_row = (const float*)d_in[0];
  const float* query_col = (const float*)d_in[1];
  const float* key_row   = (const float*)d_in[2];
  const float* key_col   = (const float*)d_in[3];
  const float* value     = (const float*)d_in[4];
  const float* W         = (const float*)d_in[5];  // (1280,256)
  const float* Bv        = (const float*)d_in[6];  // (1280,)
  const float* Wout      = (const float*)d_in[7];  // (256,256)
  const float* Bout      = (const float*)d_in[8];  // (256,)

  float* ws = (float*)d_ws;
  float* krm   = ws;                        // 196608 f
  float* kcm   = krm + 196608;              // 196608 f
  float* ao    = kcm + 196608;              // 614400 f
  float* wcolT = ao + 614400;               // 1966080 f
  short* qrb   = (short*)(wcolT + 1966080); // 614400 s
  short* qcb   = qrb + 614400;              // 614400 s
  short* krb   = qcb + 614400;              // 196608 s
  short* kcb   = krb + 196608;              // 196608 s
  short* wrowB = kcb + 196608;              // 1966080 s
  short* vvT   = wrowB + 1966080;           // 18874368 s
  short* Wb    = vvT + 18874368;            // 393216 s

  cvt_w_kernel<<<1536, 256, 0, stream>>>(W, Wout, Wb);
  mean_over_h_v3<<<768, 256, 0, stream>>>(key_row, krm);
  mean_over_w_v3<<<768, 256, 0, stream>>>(key_col, kcm);
  gemm_proj<<<dim3(75, 2), 256, 0, stream>>>(query_row, query_col, Wb, Bv,
                                             nullptr, qrb, qcb, SCALE_Q, 3);
  gemm_proj<<<dim3(24, 2), 256, 0, stream>>>(krm, kcm, Wb + 131072, Bv + 512,
                                             nullptr, krb, kcb, 1.f, 3);
  vproj_kernel<<<256, 512, 0, stream>>>(value, Wb + 262144, Bv + 1024, vvT);
  scores_softmax_v2<<<dim3(4, 64, 2), 64, 0, stream>>>(qrb, qcb, krb, kcb, wrowB, wcolT);
  attn_kernel<<<320, 512, 0, stream>>>(wrowB, wcolT, vvT, ao);
  gemm_proj<<<dim3(75, 1), 256, 0, stream>>>(ao, nullptr, Wb + 327680, Bout,
                                             (float*)d_out, nullptr, nullptr, 1.f, 1);
}

// Round 14
// 155.911 us; speedup vs baseline: 1.0294x; 1.0110x over previous
//
#include <hip/hip_runtime.h>
#include <cstdint>

// MultiheadRCDA: N=8, L=300, HH=WW=96, E=256, NH=8, HD=32
// Round 14: attn ring + per-iter memory-clobber fences (r13 VGPR=108 proved
// the compiler sank the ring refills; fences make sinking illegal). vproj:
// 2-tile Ts groups -> 50.5KB LDS -> 2 blocks/CU (16 waves/CU).

typedef __attribute__((ext_vector_type(8))) short short8v;  // bf16x8 MFMA frag
typedef __attribute__((ext_vector_type(4))) short short4v;  // 8B packed bf16
typedef __attribute__((ext_vector_type(4))) float f32x4;

#define SCALE_Q 0.17677669529663687f  // 32^-0.5

#define GLL16(gp, lp)                                                   \
  __builtin_amdgcn_global_load_lds(                                     \
      (const __attribute__((address_space(1))) void*)(gp),              \
      (__attribute__((address_space(3))) void*)(lp), 16, 0, 0)

__device__ __forceinline__ unsigned short f2bf(float x) {
  unsigned int u = __builtin_bit_cast(unsigned int, x);
  u += 0x7FFFu + ((u >> 16) & 1u);
  return (unsigned short)(u >> 16);
}

__device__ __forceinline__ unsigned int cvtpk(float a, float b) {
  unsigned int r;
  asm("v_cvt_pk_bf16_f32 %0, %1, %2" : "=v"(r) : "v"(a), "v"(b));
  return r;
}

__device__ __forceinline__ short8v pack8cvt(const f32x4& lo, const f32x4& hi) {
  union { short8v s; unsigned int u[4]; } z;
  z.u[0] = cvtpk(lo[0], lo[1]);
  z.u[1] = cvtpk(lo[2], lo[3]);
  z.u[2] = cvtpk(hi[0], hi[1]);
  z.u[3] = cvtpk(hi[2], hi[3]);
  return z.s;
}

__device__ __forceinline__ short4v pack4cvt(float a, float b, float c, float d) {
  union { short4v s; unsigned int u[2]; } z;
  z.u[0] = cvtpk(a, b);
  z.u[1] = cvtpk(c, d);
  return z.s;
}

__device__ __forceinline__ short8v pack8(const float4& fa, const float4& fb) {
  short8v v;
  v[0] = (short)f2bf(fa.x); v[1] = (short)f2bf(fa.y);
  v[2] = (short)f2bf(fa.z); v[3] = (short)f2bf(fa.w);
  v[4] = (short)f2bf(fb.x); v[5] = (short)f2bf(fb.y);
  v[6] = (short)f2bf(fb.z); v[7] = (short)f2bf(fb.w);
  return v;
}

// ---------------- weight fp32->bf16 ----------------
__global__ __launch_bounds__(256) void cvt_w_kernel(const float* __restrict__ w_in,
                                                    const float* __restrict__ w_out,
                                                    short* __restrict__ Wb) {
  int idx = blockIdx.x * 256 + threadIdx.x;  // 393216 total
  float v = (idx < 327680) ? w_in[idx] : w_out[idx - 327680];
  Wb[idx] = (short)f2bf(v);
}

// ---------------- mean kernels v3 ----------------
__global__ __launch_bounds__(256) void mean_over_h_v3(const float* __restrict__ in,
                                                      float* __restrict__ out) {
  __shared__ float4 part[256];
  int bw = blockIdx.x;  // b*96 + w
  int b = bw / 96, w = bw - b * 96;
  int t = threadIdx.x, e4 = t & 63, hq = t >> 6;
  const float4* p = (const float4*)(in + ((size_t)b * 9216 + w) * 256) + e4 +
                    (size_t)hq * 24 * 6144;
  float4 s = {0.f, 0.f, 0.f, 0.f};
#pragma unroll
  for (int i = 0; i < 24; ++i) {
    float4 v = p[(size_t)i * 6144];
    s.x += v.x; s.y += v.y; s.z += v.z; s.w += v.w;
  }
  part[t] = s;
  __syncthreads();
  if (t < 64) {
    float4 a = part[t], c = part[t + 64], d = part[t + 128], e = part[t + 192];
    float4 o;
    o.x = (a.x + c.x + d.x + e.x) * (1.f / 96.f);
    o.y = (a.y + c.y + d.y + e.y) * (1.f / 96.f);
    o.z = (a.z + c.z + d.z + e.z) * (1.f / 96.f);
    o.w = (a.w + c.w + d.w + e.w) * (1.f / 96.f);
    ((float4*)out)[(size_t)bw * 64 + t] = o;
  }
}

__global__ __launch_bounds__(256) void mean_over_w_v3(const float* __restrict__ in,
                                                      float* __restrict__ out) {
  __shared__ float4 part[256];
  int bh = blockIdx.x;  // b*96 + h
  int t = threadIdx.x, e4 = t & 63, wq = t >> 6;
  const float4* p = (const float4*)(in + (size_t)bh * 24576) + e4 + (size_t)wq * 24 * 64;
  float4 s = {0.f, 0.f, 0.f, 0.f};
#pragma unroll
  for (int i = 0; i < 24; ++i) {
    float4 v = p[(size_t)i * 64];
    s.x += v.x; s.y += v.y; s.z += v.z; s.w += v.w;
  }
  part[t] = s;
  __syncthreads();
  if (t < 64) {
    float4 a = part[t], c = part[t + 64], d = part[t + 128], e = part[t + 192];
    float4 o;
    o.x = (a.x + c.x + d.x + e.x) * (1.f / 96.f);
    o.y = (a.y + c.y + d.y + e.y) * (1.f / 96.f);
    o.z = (a.z + c.z + d.z + e.z) * (1.f / 96.f);
    o.w = (a.w + c.w + d.w + e.w) * (1.f / 96.f);
    ((float4*)out)[(size_t)bh * 64 + t] = o;
  }
}

// ---------------- bf16 MFMA projection GEMM (q/k/out), BM=32 ----------------
__global__ __launch_bounds__(256) void gemm_proj(
    const float* __restrict__ A0, const float* __restrict__ A1,
    const short* __restrict__ Wb, const float* __restrict__ bias,
    float* __restrict__ Cf, short* __restrict__ Cb0, short* __restrict__ Cb1,
    float scale, int mode) {
  __shared__ short As[32 * 264];
  int y = blockIdx.y;
  const float* A = y ? A1 : A0;
  short* Cb = y ? Cb1 : Cb0;
  const short* Wp = Wb + y * 65536;
  const float* bp = bias + y * 256;
  int t = threadIdx.x;
  int m0 = blockIdx.x * 32;
  int wave = t >> 6, lane = t & 63, r = lane & 15, g = lane >> 4;

  {
    int row = t >> 3, c0 = (t & 7) * 32;
    const float* ap = A + ((size_t)m0 + row) * 256 + c0;
    float4 ld[8];
#pragma unroll
    for (int j = 0; j < 8; ++j) ld[j] = *(const float4*)(ap + j * 4);
    short* dst = &As[row * 264 + c0];
#pragma unroll
    for (int j = 0; j < 4; ++j)
      *(short8v*)(dst + j * 8) = pack8(ld[2 * j], ld[2 * j + 1]);
  }
  __syncthreads();

  f32x4 acc[2][4] = {};
  const short* wbase = Wp + (size_t)(wave * 64 + r) * 256;
#pragma unroll
  for (int ks = 0; ks < 8; ++ks) {
    short8v af0 = *(const short8v*)&As[r * 264 + ks * 32 + g * 8];
    short8v af1 = *(const short8v*)&As[(16 + r) * 264 + ks * 32 + g * 8];
    short8v bf[4];
#pragma unroll
    for (int nf = 0; nf < 4; ++nf)
      bf[nf] = *(const short8v*)(wbase + nf * 16 * 256 + ks * 32 + g * 8);
#pragma unroll
    for (int nf = 0; nf < 4; ++nf) {
      acc[0][nf] = __builtin_amdgcn_mfma_f32_16x16x32_bf16(af0, bf[nf], acc[0][nf], 0, 0, 0);
      acc[1][nf] = __builtin_amdgcn_mfma_f32_16x16x32_bf16(af1, bf[nf], acc[1][nf], 0, 0, 0);
    }
  }

#pragma unroll
  for (int mf = 0; mf < 2; ++mf)
#pragma unroll
    for (int nf = 0; nf < 4; ++nf) {
      int nn = wave * 64 + nf * 16 + r;
      float bval = bp[nn];
#pragma unroll
      for (int i = 0; i < 4; ++i) {
        int m = m0 + mf * 16 + g * 4 + i;
        float val = (acc[mf][nf][i] + bval) * scale;
        if (mode == 1) {
          int bb = m / 300, ll = m - bb * 300;
          Cf[((size_t)ll * 8 + bb) * 256 + nn] = val;
        } else {  // mode 3
          Cb[(size_t)m * 256 + nn] = (short)f2bf(val);
        }
      }
    }
}

// ---------------- value projection v11 (2 blocks/CU) ----------------
// vvT[bn][d(32)][hw(9216)] bf16. grid 512 x 512 thr; 144 rows/block
// (9 tiles of 16); 8 waves x 32 channels; Ts 2-tile groups (64B channel
// runs); LDS 50.5KB -> 2 blocks/CU; counted vmcnt.
__global__ __launch_bounds__(512, 4) void vproj_kernel(
    const float* __restrict__ A, const short* __restrict__ Wb,
    const float* __restrict__ bias, short* __restrict__ vvT) {
  __shared__ float buf[2][16 * 260];   // 33.3 KB
  __shared__ short Ts[8][32 * 36];     // 18.4 KB: per-wave 32ch x (32hw pad36)
  int t = threadIdx.x;
  int wave = t >> 6, lane = t & 63, r = lane & 15, g = lane >> 4;
  int m0g = blockIdx.x * 144;
  int b_ = blockIdx.x >> 6;            // 64 blocks per batch (9216/144)
  int hw00 = (blockIdx.x & 63) * 144;
  int chbase = wave * 32;

  short8v bf[8][2];
  {
    const short* wbase = Wb + (size_t)(chbase + r) * 256;
#pragma unroll
    for (int ks = 0; ks < 8; ++ks)
#pragma unroll
      for (int nf = 0; nf < 2; ++nf)
        bf[ks][nf] = *(const short8v*)(wbase + nf * 16 * 256 + ks * 32 + g * 8);
  }
#pragma unroll
  for (int ks = 0; ks < 8; ++ks)
#pragma unroll
    for (int nf = 0; nf < 2; ++nf)
      asm volatile("" : "+a"(bf[ks][nf]));
  float bias_v[2];
#pragma unroll
  for (int nf = 0; nf < 2; ++nf) bias_v[nf] = bias[chbase + nf * 16 + r];

  // prologue: stage tiles 0,1; wave stages rows wave*2, wave*2+1
#pragma unroll
  for (int q = 0; q < 2; ++q) {
#pragma unroll
    for (int i = 0; i < 2; ++i) {
      int row = wave * 2 + i;
      const float* gp = A + ((size_t)m0g + q * 16 + row) * 256 + lane * 4;
      GLL16(gp, &buf[q][row * 260]);
    }
  }

  int chg = chbase + (lane & 31);
  int half = lane >> 5;
  short* vbase = vvT + (size_t)(b_ * 8 + (chg >> 5)) * 294912 +
                 (size_t)(chg & 31) * 9216 + hw00;
  const short* tsr = &Ts[wave][(lane & 31) * 36];

#pragma unroll
  for (int tt = 0; tt < 9; ++tt) {
    // counted wait for tile tt's 2 GLLs (per-wave in-order vmcnt):
    // outstanding newer ops = GLL(tt+1) [2] + stores(tt-1) [2 if tt even>=2]
    if (tt == 0 || (tt & 1) || tt == 8)
      asm volatile("s_waitcnt vmcnt(2)" ::: "memory");
    else
      asm volatile("s_waitcnt vmcnt(4)" ::: "memory");
    __builtin_amdgcn_s_barrier();

    f32x4 acc[2] = {};
    const float* bp_ = &buf[tt & 1][0];
#pragma unroll
    for (int ks = 0; ks < 8; ++ks) {
      const float* p = bp_ + r * 260 + ks * 32 + g * 8;
      f32x4 lo = *(const f32x4*)p;
      f32x4 hi = *(const f32x4*)(p + 4);
      short8v af = pack8cvt(lo, hi);
      acc[0] = __builtin_amdgcn_mfma_f32_16x16x32_bf16(af, bf[ks][0], acc[0], 0, 0, 0);
      acc[1] = __builtin_amdgcn_mfma_f32_16x16x32_bf16(af, bf[ks][1], acc[1], 0, 0, 0);
    }

    // Ts slot (tt&1)*16 (wave-private; DS in-order per wave)
#pragma unroll
    for (int nf = 0; nf < 2; ++nf) {
      float bv = bias_v[nf];
      *(short4v*)&Ts[wave][(nf * 16 + r) * 36 + (tt & 1) * 16 + g * 4] =
          pack4cvt(acc[nf][0] + bv, acc[nf][1] + bv, acc[nf][2] + bv, acc[nf][3] + bv);
    }
    asm volatile("" ::: "memory");

    if (tt & 1) {  // store tiles (tt-1, tt): 32 hw = 64B per channel
      short* gdst = vbase + (tt - 1) * 16 + half * 16;
      const short* src = tsr + half * 16;
      *(short8v*)gdst = *(const short8v*)src;
      *(short8v*)(gdst + 8) = *(const short8v*)(src + 8);
      asm volatile("" ::: "memory");
    }

    __builtin_amdgcn_s_barrier();  // all waves done reading buf[tt&1]
    if (tt + 2 < 9) {              // refill with tile tt+2
#pragma unroll
      for (int i = 0; i < 2; ++i) {
        int row = wave * 2 + i;
        const float* gp = A + ((size_t)m0g + (tt + 2) * 16 + row) * 256 + lane * 4;
        GLL16(gp, &buf[tt & 1][row * 260]);
      }
    }
  }
  // tail: tile 8 (slot 0): 16 hw = 32B per channel
  {
    short* gdst = vbase + 128 + half * 8;
    *(short8v*)gdst = *(const short8v*)(tsr + half * 8);
  }
}

// ---------------- scores + softmax: MFMA + in-register softmax ----------------
__global__ __launch_bounds__(64) void scores_softmax_v2(
    const short* __restrict__ qrb, const short* __restrict__ qcb,
    const short* __restrict__ krb, const short* __restrict__ kcb,
    short* __restrict__ wrowB, float* __restrict__ wcolT) {
  int lchunk = blockIdx.x, bn = blockIdx.y, kind = blockIdx.z;
  int b = bn >> 3, n = bn & 7;
  int lane = threadIdx.x;
  int r = lane & 15, g = lane >> 4;
  const short* qb = kind ? qcb : qrb;
  const short* kb = kind ? kcb : krb;
  int l0 = lchunk * 80;

  short8v a[5], bfr[6];
#pragma unroll
  for (int lf = 0; lf < 5; ++lf) {
    int l = l0 + lf * 16 + r;
    if (l > 299) l = 299;
    a[lf] = *(const short8v*)(qb + ((size_t)b * 300 + l) * 256 + n * 32 + g * 8);
  }
#pragma unroll
  for (int f = 0; f < 6; ++f)
    bfr[f] = *(const short8v*)(kb + ((size_t)b * 96 + f * 16 + r) * 256 + n * 32 + g * 8);

  f32x4 c[5][6];
#pragma unroll
  for (int lf = 0; lf < 5; ++lf)
#pragma unroll
    for (int f = 0; f < 6; ++f) {
      f32x4 z = {};
      c[lf][f] = __builtin_amdgcn_mfma_f32_16x16x32_bf16(a[lf], bfr[f], z, 0, 0, 0);
    }

#pragma unroll
  for (int lf = 0; lf < 5; ++lf)
#pragma unroll
    for (int i = 0; i < 4; ++i) {
      float m = c[lf][0][i];
#pragma unroll
      for (int f = 1; f < 6; ++f) m = fmaxf(m, c[lf][f][i]);
#pragma unroll
      for (int mask = 1; mask <= 8; mask <<= 1) m = fmaxf(m, __shfl_xor(m, mask, 64));
      float e[6], s = 0.f;
#pragma unroll
      for (int f = 0; f < 6; ++f) { e[f] = __expf(c[lf][f][i] - m); s += e[f]; }
#pragma unroll
      for (int mask = 1; mask <= 8; mask <<= 1) s += __shfl_xor(s, mask, 64);
      float inv = 1.f / s;
#pragma unroll
      for (int f = 0; f < 6; ++f) c[lf][f][i] = e[f] * inv;
    }

  if (kind == 0) {
#pragma unroll
    for (int lf = 0; lf < 5; ++lf)
#pragma unroll
      for (int i = 0; i < 4; ++i) {
        int l = l0 + lf * 16 + g * 4 + i;
        bool ok = (l < 300);
#pragma unroll
        for (int f = 0; f < 6; ++f) {
          float wv = ok ? c[lf][f][i] : 0.f;
          wrowB[((size_t)bn * 320 + l) * 96 + f * 16 + r] = (short)f2bf(wv);
        }
      }
  } else {
#pragma unroll
    for (int lf = 0; lf < 5; ++lf)
#pragma unroll
      for (int f = 0; f < 6; ++f) {
        int l = l0 + lf * 16 + g * 4;
        f32x4 wv = c[lf][f];
#pragma unroll
        for (int i = 0; i < 4; ++i) if (l + i >= 300) wv[i] = 0.f;
        *(f32x4*)(wcolT + ((size_t)bn * 96 + f * 16 + r) * 320 + l) = wv;
      }
  }
}

// ---------------- fused bilinear attention (fenced depth-4 ring) ----------
__global__ __launch_bounds__(512, 2) void attn_kernel(
    const short* __restrict__ wrowB, const float* __restrict__ wcolT,
    const short* __restrict__ vvT, float* __restrict__ ao) {
  __shared__ f32x4 cmb[3][2][4][64];
  int i = blockIdx.x;
  int xcd = i & 7, j = i >> 3;
  int bn = (j / 5) * 8 + xcd;
  int lh = j - (j / 5) * 5;
  int b = bn >> 3, n = bn & 7;
  int t = threadIdx.x, wave = t >> 6, lane = t & 63;
  int df = wave & 1, hh = wave >> 1;
  int lbase = lh * 64;
  int r = lane & 15, g = lane >> 4;

  short8v a[4][3];
  const short* wr = wrowB + (size_t)bn * 320 * 96;
#pragma unroll
  for (int lf = 0; lf < 4; ++lf)
#pragma unroll
    for (int ks = 0; ks < 3; ++ks)
      a[lf][ks] = *(const short8v*)(wr + (lbase + lf * 16 + r) * 96 + ks * 32 + g * 8);

  const short* vb = vvT + (size_t)bn * 294912 + (size_t)(df * 16 + r) * 9216 + hh * 24 * 96;
  const float* wcb = wcolT + ((size_t)bn * 96 + hh * 24) * 320 + lbase + g * 4;

  f32x4 acc[4] = {};
  short8v bR[4][3];
  f32x4 wR[4][4];
  // prologue: fill 4-deep ring (h-steps 0..3); fence pins the loads here
#pragma unroll
  for (int q = 0; q < 4; ++q) {
#pragma unroll
    for (int ks = 0; ks < 3; ++ks)
      bR[q][ks] = *(const short8v*)(vb + q * 96 + ks * 32 + g * 8);
#pragma unroll
    for (int lf = 0; lf < 4; ++lf)
      wR[q][lf] = *(const f32x4*)(wcb + q * 320 + lf * 16);
  }
  asm volatile("" ::: "memory");

#pragma unroll
  for (int hs = 0; hs < 24; ++hs) {
    int cur = hs & 3;  // compile-time after full unroll
    f32x4 R[4] = {};
#pragma unroll
    for (int ks = 0; ks < 3; ++ks)
#pragma unroll
      for (int lf = 0; lf < 4; ++lf)
        R[lf] = __builtin_amdgcn_mfma_f32_16x16x32_bf16(a[lf][ks], bR[cur][ks], R[lf], 0, 0, 0);
#pragma unroll
    for (int lf = 0; lf < 4; ++lf) acc[lf] += wR[cur][lf] * R[lf];
    if (hs + 4 < 24) {  // refill freed slot with h-step hs+4
#pragma unroll
      for (int ks = 0; ks < 3; ++ks)
        bR[cur][ks] = *(const short8v*)(vb + (hs + 4) * 96 + ks * 32 + g * 8);
#pragma unroll
      for (int lf = 0; lf < 4; ++lf)
        wR[cur][lf] = *(const f32x4*)(wcb + (hs + 4) * 320 + lf * 16);
    }
    // fence: refill loads cannot sink past end of this iteration
    asm volatile("" ::: "memory");
  }

  if (hh > 0) {
#pragma unroll
    for (int lf = 0; lf < 4; ++lf) cmb[hh - 1][df][lf][lane] = acc[lf];
  }
  __syncthreads();
  if (hh == 0) {
#pragma unroll
    for (int lf = 0; lf < 4; ++lf) {
      f32x4 o = acc[lf];
#pragma unroll
      for (int q = 0; q < 3; ++q) o += cmb[q][df][lf][lane];
#pragma unroll
      for (int i2 = 0; i2 < 4; ++i2) {
        int l = lbase + lf * 16 + g * 4 + i2;
        if (l < 300)
          ao[((size_t)b * 300 + l) * 256 + n * 32 + df * 16 + r] = o[i2];
      }
    }
  }
}

// ---------------- launch ----------------
extern "C" void kernel_launch(void* const* d_in, const int* in_sizes, int n_in,
                              void* d_out, int out_size, void* d_ws, size_t ws_size,
                              hipStream_t stream) {
  const float* query_row = (const float*)d_in[0];
  const float* query_col = (const float*)d_in[1];
  const float* key_row   = (const float*)d_in[2];
  const float* key_col   = (const float*)d_in[3];
  const float* value     = (const float*)d_in[4];
  const float* W         = (const float*)d_in[5];  // (1280,256)
  const float* Bv        = (const float*)d_in[6];  // (1280,)
  const float* Wout      = (const float*)d_in[7];  // (256,256)
  const float* Bout      = (const float*)d_in[8];  // (256,)

  float* ws = (float*)d_ws;
  float* krm   = ws;                        // 196608 f
  float* kcm   = krm + 196608;              // 196608 f
  float* ao    = kcm + 196608;              // 614400 f
  float* wcolT = ao + 614400;               // 1966080 f
  short* qrb   = (short*)(wcolT + 1966080); // 614400 s
  short* qcb   = qrb + 614400;              // 614400 s
  short* krb   = qcb + 614400;              // 196608 s
  short* kcb   = krb + 196608;              // 196608 s
  short* wrowB = kcb + 196608;              // 1966080 s
  short* vvT   = wrowB + 1966080;           // 18874368 s
  short* Wb    = vvT + 18874368;            // 393216 s

  cvt_w_kernel<<<1536, 256, 0, stream>>>(W, Wout, Wb);
  mean_over_h_v3<<<768, 256, 0, stream>>>(key_row, krm);
  mean_over_w_v3<<<768, 256, 0, stream>>>(key_col, kcm);
  gemm_proj<<<dim3(75, 2), 256, 0, stream>>>(query_row, query_col, Wb, Bv,
                                             nullptr, qrb, qcb, SCALE_Q, 3);
  gemm_proj<<<dim3(24, 2), 256, 0, stream>>>(krm, kcm, Wb + 131072, Bv + 512,
                                             nullptr, krb, kcb, 1.f, 3);
  vproj_kernel<<<512, 512, 0, stream>>>(value, Wb + 262144, Bv + 1024, vvT);
  scores_softmax_v2<<<dim3(4, 64, 2), 64, 0, stream>>>(qrb, qcb, krb, kcb, wrowB, wcolT);
  attn_kernel<<<320, 512, 0, stream>>>(wrowB, wcolT, vvT, ao);
  gemm_proj<<<dim3(75, 1), 256, 0, stream>>>(ao, nullptr, Wb + 327680, Bout,
                                             (float*)d_out, nullptr, nullptr, 1.f, 1);
}